// Round 7
// baseline (9554.214 us; speedup 1.0000x reference)
//
#include <hip/hip_runtime.h>
#include <hip/hip_bf16.h>

#define BB 16
#define TT 1024
#define FF 128
#define RR 2048
#define HALFR 1024
#define NBLK 256
#define NTHR 512

// ---- coherent (IC-level) memory ops: bypass L1/L2, no fences needed ----
__device__ __forceinline__ float4 ldg_sc4(const float* base, unsigned voff) {
    float4 r;
    asm volatile("global_load_dwordx4 %0, %1, %2 sc0 sc1"
                 : "=v"(r) : "v"(voff), "s"(base) : "memory");
    return r;
}
__device__ __forceinline__ float ldg_sc1(const float* base, unsigned voff) {
    float r;
    asm volatile("global_load_dword %0, %1, %2 sc0 sc1"
                 : "=v"(r) : "v"(voff), "s"(base) : "memory");
    return r;
}
__device__ __forceinline__ void stg_sc1(float* base, unsigned voff, float v) {
    asm volatile("global_store_dword %0, %1, %2 sc0 sc1"
                 :: "v"(voff), "v"(v), "s"(base) : "memory");
}
__device__ __forceinline__ uint4 ldg_scu4(const unsigned* base, unsigned voff) {
    uint4 r;
    asm volatile("global_load_dwordx4 %0, %1, %2 sc0 sc1"
                 : "=v"(r) : "v"(voff), "s"(base) : "memory");
    return r;
}
__device__ __forceinline__ void stg_scu1(unsigned* base, unsigned voff, unsigned v) {
    asm volatile("global_store_dword %0, %1, %2 sc0 sc1"
                 :: "v"(voff), "v"(v), "s"(base) : "memory");
}
__device__ __forceinline__ void wait_vm0() {
    asm volatile("s_waitcnt vmcnt(0)" ::: "memory");
}

// ---------------- init: h0 + barrier words ----------------
__global__ void init_state_kernel(float* __restrict__ h, const float* __restrict__ start,
                                  unsigned* __restrict__ bar) {
    int idx = blockIdx.x * blockDim.x + threadIdx.x;
    if (idx < BB * RR) h[idx] = start[idx & (RR - 1)];
    if (idx < 2048) bar[idx] = 0u;
}

// ---------------- persistent fp32 ESN kernel (R5 body + store-only barrier) --
// 256 blocks x 512 threads, 1 block/CU, cooperative. Block owns 8 rows of
// W_rec in LDS. Wave = 4 rows x 4 batches (R5-proven tiling). Barrier v3:
// NO atomics at all — block b stores done[b]=t+1 (coherent store, own word);
// wave 0 polls all 256 words with one coalesced 1KB dwordx4 coherent load
// (lane L covers words 4L..4L+3), min>=t+1 ballot. Monotone values make
// overwrites safe; one barrier/step is sufficient with h ping-pong.
__global__ __launch_bounds__(NTHR, 2) void esn_f32(
    const float* __restrict__ inputs,   // [B,T,F]
    const float* __restrict__ Win,      // [R,F]
    const float* __restrict__ Wrec,     // [R,R]
    const float* __restrict__ bias,     // [R]
    float* __restrict__ hA,             // [B,R]
    float* __restrict__ hB,             // [B,R]
    float* __restrict__ out,            // [B,T,HALFR]
    unsigned* __restrict__ bar)
{
    __shared__ __align__(16) float sW[8][RR];     // 64 KB
    __shared__ __align__(16) float sWin[8][FF];   // 4 KB

    const int tid  = threadIdx.x;
    const int lane = tid & 63;
    const int wave = tid >> 6;           // 0..7
    const int rg   = wave & 1;           // row group (4 rows)
    const int bq   = (wave >> 1) * 4;    // batch base 0,4,8,12
    const int r0b  = blockIdx.x * 8;
    const bool proj = (r0b < HALFR);

    // Stage W + Win into LDS once (reused for all 1024 steps).
    {
        const float4* wsrc = (const float4*)(Wrec + (size_t)r0b * RR);
        float4* wdst = (float4*)sW;
        for (int i = tid; i < (8 * RR) / 4; i += NTHR) wdst[i] = wsrc[i];
        const float4* wis = (const float4*)(Win + (size_t)r0b * FF);
        float4* wid = (float4*)sWin;
        for (int i = tid; i < (8 * FF) / 4; i += NTHR) wid[i] = wis[i];
    }
    __syncthreads();

    const bool hi32 = (lane & 32) != 0;
    const bool hi16 = (lane & 16) != 0;
    const bool hi8  = (lane & 8) != 0;
    const bool hi4  = (lane & 4) != 0;
    const int rOut = r0b + rg * 4 + (hi32 ? 2 : 0) + (hi8 ? 1 : 0);
    const int bOut = bq + (hi16 ? 2 : 0) + (hi4 ? 1 : 0);
    const float myBias = bias[rOut];

    // Loop-invariant byte offsets for the coherent h accesses.
    unsigned voff[4][8];
#pragma unroll
    for (int i = 0; i < 4; ++i)
#pragma unroll
        for (int j = 0; j < 8; ++j)
            voff[i][j] = (unsigned)((bq + i) * RR * 4 + j * 1024 + lane * 16);
    const unsigned voffOld = (unsigned)((bOut * RR + rOut) * 4);

    unsigned* done = bar;                 // words 0..255, one per block
    const unsigned pollOff = (unsigned)(lane * 16);
    const unsigned myDoneOff = (unsigned)(blockIdx.x * 4);

    for (int t = 0; t < TT; ++t) {
        const float* hc = (t & 1) ? hB : hA;
        float*       hn = (t & 1) ? hA : hB;

        // 1) Issue ALL coherent h loads up front (33 in flight).
        float4 hbuf[4][8];
#pragma unroll
        for (int i = 0; i < 4; ++i)
#pragma unroll
            for (int j = 0; j < 8; ++j)
                hbuf[i][j] = ldg_sc4(hc, voff[i][j]);
        const float hold = ldg_sc1(hc, voffOld);

        float acc[4][4];
#pragma unroll
        for (int i = 0; i < 4; ++i)
#pragma unroll
            for (int j = 0; j < 4; ++j) acc[i][j] = 0.0f;

        // 2) Input projection overlaps the h-load latency (L2-warm loads).
        if (proj && lane < 32) {
            const int k = lane * 4;
            float4 xv[4];
#pragma unroll
            for (int i = 0; i < 4; ++i)
                xv[i] = *(const float4*)(inputs + ((size_t)(bq + i) * TT + t) * FF + k);
#pragma unroll
            for (int rr = 0; rr < 4; ++rr) {
                const float4 wv = *(const float4*)&sWin[rg * 4 + rr][k];
#pragma unroll
                for (int bb = 0; bb < 4; ++bb) {
                    float a = acc[rr][bb];
                    a = fmaf(wv.x, xv[bb].x, a); a = fmaf(wv.y, xv[bb].y, a);
                    a = fmaf(wv.z, xv[bb].z, a); a = fmaf(wv.w, xv[bb].w, a);
                    acc[rr][bb] = a;
                }
            }
        }

        // 3) Drain the prefetch batch, then the MAC loop (W from LDS).
        wait_vm0();
#pragma unroll
        for (int j = 0; j < 8; ++j) {
            const int k = lane * 4 + j * 256;
            float4 wv[4];
#pragma unroll
            for (int i = 0; i < 4; ++i) wv[i] = *(const float4*)&sW[rg * 4 + i][k];
#pragma unroll
            for (int rr = 0; rr < 4; ++rr)
#pragma unroll
                for (int bb = 0; bb < 4; ++bb) {
                    float a = acc[rr][bb];
                    a = fmaf(wv[rr].x, hbuf[bb][j].x, a);
                    a = fmaf(wv[rr].y, hbuf[bb][j].y, a);
                    a = fmaf(wv[rr].z, hbuf[bb][j].z, a);
                    a = fmaf(wv[rr].w, hbuf[bb][j].w, a);
                    acc[rr][bb] = a;
                }
        }

        // 4) Multi-value fold: 16 accs over 64 lanes in 24 shuffles (R4/R5-verified).
        float s[2][4];
#pragma unroll
        for (int jb = 0; jb < 4; ++jb)
#pragma unroll
            for (int i = 0; i < 2; ++i) {
                const float u = __shfl_xor(acc[i][jb], 32);
                const float v = __shfl_xor(acc[i + 2][jb], 32);
                s[i][jb] = hi32 ? (acc[i + 2][jb] + v) : (acc[i][jb] + u);
            }
        float c2[2][2];
#pragma unroll
        for (int i = 0; i < 2; ++i)
#pragma unroll
            for (int jb = 0; jb < 2; ++jb) {
                const float u = __shfl_xor(s[i][jb], 16);
                const float v = __shfl_xor(s[i][jb + 2], 16);
                c2[i][jb] = hi16 ? (s[i][jb + 2] + v) : (s[i][jb] + u);
            }
        float d2[2];
#pragma unroll
        for (int jb = 0; jb < 2; ++jb) {
            const float u = __shfl_xor(c2[0][jb], 8);
            const float v = __shfl_xor(c2[1][jb], 8);
            d2[jb] = hi8 ? (c2[1][jb] + v) : (c2[0][jb] + u);
        }
        float e;
        {
            const float u = __shfl_xor(d2[0], 4);
            const float v = __shfl_xor(d2[1], 4);
            e = hi4 ? (d2[1] + v) : (d2[0] + u);
        }
        e += __shfl_xor(e, 2);
        e += __shfl_xor(e, 1);

        // 5) Epilogue: coherent h_next store; cached out store.
        if ((lane & 3) == 0) {
            const float pre = e + myBias;
            const float vnew = 0.05f * hold + 0.95f * tanhf(pre);
            stg_sc1(hn, voffOld, vnew);
            if (rOut >= HALFR)
                out[((size_t)bOut * TT + t) * HALFR + (rOut - HALFR)] = vnew;
        }

        // 6) Drain wave's h stores (ack at coherence point), block-sync,
        //    then store-only grid barrier.
        wait_vm0();
        __syncthreads();
        const unsigned tgt = (unsigned)(t + 1);
        if (tid == 0) stg_scu1(done, myDoneOff, tgt);
        if (wave == 0) {
            while (true) {
                uint4 d = ldg_scu4(done, pollOff);
                wait_vm0();
                unsigned m0 = d.x < d.y ? d.x : d.y;
                unsigned m1 = d.z < d.w ? d.z : d.w;
                unsigned m  = m0 < m1 ? m0 : m1;
                if (__ballot(m >= tgt) == ~0ull) break;
                __builtin_amdgcn_s_sleep(1);
            }
        }
        __syncthreads();
    }
}

// ---------------- fallback path (proven R1): fp32, 1024 launches ----------------

__global__ void init_h_kernel(float* __restrict__ h, const float* __restrict__ start) {
    int idx = blockIdx.x * blockDim.x + threadIdx.x;
    if (idx < BB * RR) h[idx] = start[idx & (RR - 1)];
}

__global__ __launch_bounds__(512, 2) void step_kernel(
    const float* __restrict__ inputs, const float* __restrict__ Win,
    const float* __restrict__ Wrec, const float* __restrict__ bias,
    const float* __restrict__ h_cur, float* __restrict__ h_next,
    float* __restrict__ out, int t)
{
    const int tid  = threadIdx.x;
    const int wave = tid >> 6;
    const int half = (tid >> 5) & 1;
    const int kl   = tid & 31;
    const int b    = wave * 2 + half;
    const int r0   = blockIdx.x * 8;

    float acc[8];
#pragma unroll
    for (int r = 0; r < 8; ++r) acc[r] = 0.0f;

    if (r0 < HALFR) {
        const float4 in4 = *reinterpret_cast<const float4*>(
            inputs + ((size_t)b * TT + t) * FF + kl * 4);
#pragma unroll
        for (int r = 0; r < 8; ++r) {
            const float4 w4 = *reinterpret_cast<const float4*>(
                Win + (size_t)(r0 + r) * FF + kl * 4);
            acc[r] += in4.x * w4.x + in4.y * w4.y + in4.z * w4.z + in4.w * w4.w;
        }
    }

    const float* hb = h_cur + (size_t)b * RR;
#pragma unroll 2
    for (int j = 0; j < 16; ++j) {
        const int k = kl * 4 + j * 128;
        const float4 h4 = *reinterpret_cast<const float4*>(hb + k);
#pragma unroll
        for (int r = 0; r < 8; ++r) {
            const float4 w4 = *reinterpret_cast<const float4*>(
                Wrec + (size_t)(r0 + r) * RR + k);
            acc[r] = fmaf(h4.x, w4.x, acc[r]);
            acc[r] = fmaf(h4.y, w4.y, acc[r]);
            acc[r] = fmaf(h4.z, w4.z, acc[r]);
            acc[r] = fmaf(h4.w, w4.w, acc[r]);
        }
    }

#pragma unroll
    for (int r = 0; r < 8; ++r) {
        float v = acc[r];
        v += __shfl_xor(v, 1);  v += __shfl_xor(v, 2);
        v += __shfl_xor(v, 4);  v += __shfl_xor(v, 8);
        v += __shfl_xor(v, 16);
        acc[r] = v;
    }

    __shared__ float red[BB][8];
    if (kl == 0) {
#pragma unroll
        for (int r = 0; r < 8; ++r) red[b][r] = acc[r];
    }
    __syncthreads();

    if (tid < BB * 8) {
        const int rr = tid & 7, bb = tid >> 3;
        const int r  = r0 + rr;
        const float pre = red[bb][rr] + bias[r];
        const float h_old = h_cur[(size_t)bb * RR + r];
        const float hn = 0.05f * h_old + 0.95f * tanhf(pre);
        h_next[(size_t)bb * RR + r] = hn;
        if (r0 >= HALFR) out[((size_t)bb * TT + t) * HALFR + (r - HALFR)] = hn;
    }
}

// ---------------- launch ----------------

extern "C" void kernel_launch(void* const* d_in, const int* in_sizes, int n_in,
                              void* d_out, int out_size, void* d_ws, size_t ws_size,
                              hipStream_t stream) {
    const float* inputs = (const float*)d_in[0];   // [B,T,F]
    const float* Win    = (const float*)d_in[1];   // [R,F]
    const float* Wrec   = (const float*)d_in[2];   // [R,R]
    const float* bias   = (const float*)d_in[3];   // [R]
    const float* start  = (const float*)d_in[4];   // [R]
    float* out = (float*)d_out;                    // [B,T,HALFR]

    float* hA = (float*)d_ws;                      // [B,R] fp32
    float* hB = hA + (size_t)BB * RR;              // [B,R] fp32
    unsigned* bar = (unsigned*)(hB + (size_t)BB * RR);
    const size_t need = (size_t)BB * RR * 4 * 2 + 8192;

    if (ws_size >= need) {
        init_state_kernel<<<64, 512, 0, stream>>>(hA, start, bar);
        void* args[] = { (void*)&inputs, (void*)&Win, (void*)&Wrec, (void*)&bias,
                         (void*)&hA, (void*)&hB, (void*)&out, (void*)&bar };
        hipLaunchCooperativeKernel((void*)esn_f32, dim3(NBLK), dim3(NTHR),
                                   args, 0, stream);
    } else {
        init_h_kernel<<<(BB * RR + 255) / 256, 256, 0, stream>>>(hA, start);
        for (int t = 0; t < TT; ++t) {
            const float* hc = (t & 1) ? hB : hA;
            float*       hn = (t & 1) ? hA : hB;
            step_kernel<<<256, 512, 0, stream>>>(inputs, Win, Wrec, bias, hc, hn, out, t);
        }
    }
}

// Round 10
// 6276.120 us; speedup vs baseline: 1.5223x; 1.5223x over previous
//
#include <hip/hip_runtime.h>
#include <hip/hip_bf16.h>

#define BB 16
#define TT 1024
#define FF 128
#define RR 2048
#define HALFR 1024
#define NBLK 256
#define NTHR 512

// ---- coherent (IC-level) memory ops: bypass L1/L2, no fences needed ----
__device__ __forceinline__ float4 ldg_sc4(const float* base, unsigned voff) {
    float4 r;
    asm volatile("global_load_dwordx4 %0, %1, %2 sc0 sc1"
                 : "=v"(r) : "v"(voff), "s"(base) : "memory");
    return r;
}
__device__ __forceinline__ float ldg_sc1(const float* base, unsigned voff) {
    float r;
    asm volatile("global_load_dword %0, %1, %2 sc0 sc1"
                 : "=v"(r) : "v"(voff), "s"(base) : "memory");
    return r;
}
__device__ __forceinline__ void stg_sc1(float* base, unsigned voff, float v) {
    asm volatile("global_store_dword %0, %1, %2 sc0 sc1"
                 :: "v"(voff), "v"(v), "s"(base) : "memory");
}
__device__ __forceinline__ void wait_vm0() {
    asm volatile("s_waitcnt vmcnt(0)" ::: "memory");
}

// ---------------- init: h0 + barrier words ----------------
__global__ void init_state_kernel(float* __restrict__ h, const float* __restrict__ start,
                                  unsigned* __restrict__ bar) {
    int idx = blockIdx.x * blockDim.x + threadIdx.x;
    if (idx < BB * RR) h[idx] = start[idx & (RR - 1)];
    if (idx < 2048) bar[idx] = 0u;
}

// ---------------- persistent fp32 ESN kernel ----------------
// 256 blocks x 512 threads, 1 block/CU, cooperative. Block owns 8 rows of
// W_rec in LDS. R10 change vs R5 (ONE variable): wave = 8 rows x 2 batches
// x full-k (wave w owns batches 2w, 2w+1) -> no two waves share a batch ->
// every h element read exactly ONCE per block per step (128 KB coherent IC
// reads vs R5's duplicated 256 KB). hbuf halves to 16 float4. Accumulators
// stay 16; fold is R5's proven 4-select + 2-butterfly idiom with levels
// relabeled (32/16/8 = row bits, 4 = batch bit); epilogue, staging and the
// two-level all-relaxed RMW barrier are byte-for-byte R5. Known trade: W
// LDS reads double (512 b128/CU/step) — LDS pipe overlaps VALU and is
// cheaper than the duplicated IC traffic it replaces.
__global__ __launch_bounds__(NTHR, 2) void esn_f32(
    const float* __restrict__ inputs,   // [B,T,F]
    const float* __restrict__ Win,      // [R,F]
    const float* __restrict__ Wrec,     // [R,R]
    const float* __restrict__ bias,     // [R]
    float* __restrict__ hA,             // [B,R]
    float* __restrict__ hB,             // [B,R]
    float* __restrict__ out,            // [B,T,HALFR]
    unsigned* __restrict__ bar)
{
    __shared__ __align__(16) float sW[8][RR];     // 64 KB
    __shared__ __align__(16) float sWin[8][FF];   // 4 KB

    const int tid  = threadIdx.x;
    const int lane = tid & 63;
    const int wave = tid >> 6;           // 0..7
    const int b0   = wave * 2;           // this wave's two batches
    const int r0b  = blockIdx.x * 8;
    const bool proj = (r0b < HALFR);

    // Stage W + Win into LDS once (reused for all 1024 steps).
    {
        const float4* wsrc = (const float4*)(Wrec + (size_t)r0b * RR);
        float4* wdst = (float4*)sW;
        for (int i = tid; i < (8 * RR) / 4; i += NTHR) wdst[i] = wsrc[i];
        const float4* wis = (const float4*)(Win + (size_t)r0b * FF);
        float4* wid = (float4*)sWin;
        for (int i = tid; i < (8 * FF) / 4; i += NTHR) wid[i] = wis[i];
    }
    __syncthreads();

    const bool hi32 = (lane & 32) != 0;
    const bool hi16 = (lane & 16) != 0;
    const bool hi8  = (lane & 8) != 0;
    const bool hi4  = (lane & 4) != 0;
    // After the fold: row bits <- lane bits 32/16/8; batch bit <- 4.
    const int rOut = r0b + (hi32 ? 4 : 0) + (hi16 ? 2 : 0) + (hi8 ? 1 : 0);
    const int bOut = b0 + (hi4 ? 1 : 0);
    const float myBias = bias[rOut];
    const unsigned voffOld = (unsigned)((bOut * RR + rOut) * 4);

    // Coherent h-load offsets: batch b0+b, k = j*256 + lane*4.
    unsigned voffH[2][8];
#pragma unroll
    for (int b = 0; b < 2; ++b)
#pragma unroll
        for (int j = 0; j < 8; ++j)
            voffH[b][j] = (unsigned)((((b0 + b) * RR) + j * 256 + lane * 4) * 4);

    // R5 two-level barrier state (all-relaxed; each word on its own 128B line).
    const unsigned g = blockIdx.x & 15u;
    unsigned* grpCnt      = bar + g * 32;
    unsigned* masterCnt   = bar + 16 * 32;
    unsigned* masterEpoch = bar + 17 * 32;
    unsigned* grpEpoch    = bar + (18 + g) * 32;

    for (int t = 0; t < TT; ++t) {
        const float* hc = (t & 1) ? hB : hA;
        float*       hn = (t & 1) ? hA : hB;

        // 1) Issue ALL coherent h loads up front (17 in flight).
        float4 hbuf[2][8];
#pragma unroll
        for (int b = 0; b < 2; ++b)
#pragma unroll
            for (int j = 0; j < 8; ++j)
                hbuf[b][j] = ldg_sc4(hc, voffH[b][j]);
        const float hold = ldg_sc1(hc, voffOld);

        float acc[8][2];
#pragma unroll
        for (int r = 0; r < 8; ++r)
#pragma unroll
            for (int b = 0; b < 2; ++b) acc[r][b] = 0.0f;

        // 2) Input projection (lanes 0..31 cover F=128) overlaps load latency.
        if (proj && lane < 32) {
            const int k = lane * 4;
            float4 xv[2];
#pragma unroll
            for (int b = 0; b < 2; ++b)
                xv[b] = *(const float4*)(inputs + ((size_t)(b0 + b) * TT + t) * FF + k);
#pragma unroll
            for (int r = 0; r < 8; ++r) {
                const float4 wv = *(const float4*)&sWin[r][k];
#pragma unroll
                for (int b = 0; b < 2; ++b) {
                    float a = acc[r][b];
                    a = fmaf(wv.x, xv[b].x, a); a = fmaf(wv.y, xv[b].y, a);
                    a = fmaf(wv.z, xv[b].z, a); a = fmaf(wv.w, xv[b].w, a);
                    acc[r][b] = a;
                }
            }
        }

        // 3) Drain the prefetch batch, then the MAC loop (W from LDS).
        wait_vm0();
#pragma unroll
        for (int j = 0; j < 8; ++j) {
            const int k = j * 256 + lane * 4;
            float4 wv[8];
#pragma unroll
            for (int r = 0; r < 8; ++r) wv[r] = *(const float4*)&sW[r][k];
#pragma unroll
            for (int r = 0; r < 8; ++r)
#pragma unroll
                for (int b = 0; b < 2; ++b) {
                    float a = acc[r][b];
                    a = fmaf(wv[r].x, hbuf[b][j].x, a);
                    a = fmaf(wv[r].y, hbuf[b][j].y, a);
                    a = fmaf(wv[r].z, hbuf[b][j].z, a);
                    a = fmaf(wv[r].w, hbuf[b][j].w, a);
                    acc[r][b] = a;
                }
        }

        // 4) Fold: R5's proven 4-select + 2-butterfly idiom, levels relabeled.
        // Level 32: row bit2
        float f1[4][2];
#pragma unroll
        for (int r = 0; r < 4; ++r)
#pragma unroll
            for (int b = 0; b < 2; ++b) {
                const float u = __shfl_xor(acc[r][b], 32);
                const float v = __shfl_xor(acc[r + 4][b], 32);
                f1[r][b] = hi32 ? (acc[r + 4][b] + v) : (acc[r][b] + u);
            }
        // Level 16: row bit1
        float f2[2][2];
#pragma unroll
        for (int r = 0; r < 2; ++r)
#pragma unroll
            for (int b = 0; b < 2; ++b) {
                const float u = __shfl_xor(f1[r][b], 16);
                const float v = __shfl_xor(f1[r + 2][b], 16);
                f2[r][b] = hi16 ? (f1[r + 2][b] + v) : (f1[r][b] + u);
            }
        // Level 8: row bit0
        float f3[2];
#pragma unroll
        for (int b = 0; b < 2; ++b) {
            const float u = __shfl_xor(f2[0][b], 8);
            const float v = __shfl_xor(f2[1][b], 8);
            f3[b] = hi8 ? (f2[1][b] + v) : (f2[0][b] + u);
        }
        // Level 4: batch bit0
        float e;
        {
            const float u = __shfl_xor(f3[0], 4);
            const float v = __shfl_xor(f3[1], 4);
            e = hi4 ? (f3[1] + v) : (f3[0] + u);
        }
        // Levels 2,1: pure k butterflies
        e += __shfl_xor(e, 2);
        e += __shfl_xor(e, 1);

        // 5) Epilogue: coherent h_next store; cached out store. (R5 flow)
        if ((lane & 3) == 0) {
            const float pre = e + myBias;
            const float vnew = 0.05f * hold + 0.95f * tanhf(pre);
            stg_sc1(hn, voffOld, vnew);
            if (rOut >= HALFR)
                out[((size_t)bOut * TT + t) * HALFR + (rOut - HALFR)] = vnew;
        }

        // 6) Drain stores, block-sync, R5 two-level all-relaxed grid barrier.
        wait_vm0();
        __syncthreads();
        if (tid == 0) {
            const unsigned tgt = (unsigned)(t + 1);
            const unsigned old = __hip_atomic_fetch_add(grpCnt, 1u, __ATOMIC_RELAXED,
                                                        __HIP_MEMORY_SCOPE_AGENT);
            if (old == tgt * 16u - 1u) {                   // last arriver in group
                const unsigned mo = __hip_atomic_fetch_add(masterCnt, 1u, __ATOMIC_RELAXED,
                                                           __HIP_MEMORY_SCOPE_AGENT);
                if (mo == tgt * 16u - 1u) {                // last group overall
                    __hip_atomic_store(masterEpoch, tgt, __ATOMIC_RELAXED,
                                       __HIP_MEMORY_SCOPE_AGENT);
                } else {
                    while (__hip_atomic_load(masterEpoch, __ATOMIC_RELAXED,
                                             __HIP_MEMORY_SCOPE_AGENT) < tgt)
                        __builtin_amdgcn_s_sleep(2);
                }
                __hip_atomic_store(grpEpoch, tgt, __ATOMIC_RELAXED,
                                   __HIP_MEMORY_SCOPE_AGENT);
            } else {
                while (__hip_atomic_load(grpEpoch, __ATOMIC_RELAXED,
                                         __HIP_MEMORY_SCOPE_AGENT) < tgt)
                    __builtin_amdgcn_s_sleep(2);
            }
        }
        __syncthreads();
    }
}

// ---------------- fallback path (proven R1): fp32, 1024 launches ----------------

__global__ void init_h_kernel(float* __restrict__ h, const float* __restrict__ start) {
    int idx = blockIdx.x * blockDim.x + threadIdx.x;
    if (idx < BB * RR) h[idx] = start[idx & (RR - 1)];
}

__global__ __launch_bounds__(512, 2) void step_kernel(
    const float* __restrict__ inputs, const float* __restrict__ Win,
    const float* __restrict__ Wrec, const float* __restrict__ bias,
    const float* __restrict__ h_cur, float* __restrict__ h_next,
    float* __restrict__ out, int t)
{
    const int tid  = threadIdx.x;
    const int wave = tid >> 6;
    const int half = (tid >> 5) & 1;
    const int kl   = tid & 31;
    const int b    = wave * 2 + half;
    const int r0   = blockIdx.x * 8;

    float acc[8];
#pragma unroll
    for (int r = 0; r < 8; ++r) acc[r] = 0.0f;

    if (r0 < HALFR) {
        const float4 in4 = *reinterpret_cast<const float4*>(
            inputs + ((size_t)b * TT + t) * FF + kl * 4);
#pragma unroll
        for (int r = 0; r < 8; ++r) {
            const float4 w4 = *reinterpret_cast<const float4*>(
                Win + (size_t)(r0 + r) * FF + kl * 4);
            acc[r] += in4.x * w4.x + in4.y * w4.y + in4.z * w4.z + in4.w * w4.w;
        }
    }

    const float* hb = h_cur + (size_t)b * RR;
#pragma unroll 2
    for (int j = 0; j < 16; ++j) {
        const int k = kl * 4 + j * 128;
        const float4 h4 = *reinterpret_cast<const float4*>(hb + k);
#pragma unroll
        for (int r = 0; r < 8; ++r) {
            const float4 w4 = *reinterpret_cast<const float4*>(
                Wrec + (size_t)(r0 + r) * RR + k);
            acc[r] = fmaf(h4.x, w4.x, acc[r]);
            acc[r] = fmaf(h4.y, w4.y, acc[r]);
            acc[r] = fmaf(h4.z, w4.z, acc[r]);
            acc[r] = fmaf(h4.w, w4.w, acc[r]);
        }
    }

#pragma unroll
    for (int r = 0; r < 8; ++r) {
        float v = acc[r];
        v += __shfl_xor(v, 1);  v += __shfl_xor(v, 2);
        v += __shfl_xor(v, 4);  v += __shfl_xor(v, 8);
        v += __shfl_xor(v, 16);
        acc[r] = v;
    }

    __shared__ float red[BB][8];
    if (kl == 0) {
#pragma unroll
        for (int r = 0; r < 8; ++r) red[b][r] = acc[r];
    }
    __syncthreads();

    if (tid < BB * 8) {
        const int rr = tid & 7, bb = tid >> 3;
        const int r  = r0 + rr;
        const float pre = red[bb][rr] + bias[r];
        const float h_old = h_cur[(size_t)bb * RR + r];
        const float hn = 0.05f * h_old + 0.95f * tanhf(pre);
        h_next[(size_t)bb * RR + r] = hn;
        if (r0 >= HALFR) out[((size_t)bb * TT + t) * HALFR + (r - HALFR)] = hn;
    }
}

// ---------------- launch ----------------

extern "C" void kernel_launch(void* const* d_in, const int* in_sizes, int n_in,
                              void* d_out, int out_size, void* d_ws, size_t ws_size,
                              hipStream_t stream) {
    const float* inputs = (const float*)d_in[0];   // [B,T,F]
    const float* Win    = (const float*)d_in[1];   // [R,F]
    const float* Wrec   = (const float*)d_in[2];   // [R,R]
    const float* bias   = (const float*)d_in[3];   // [R]
    const float* start  = (const float*)d_in[4];   // [R]
    float* out = (float*)d_out;                    // [B,T,HALFR]

    float* hA = (float*)d_ws;                      // [B,R] fp32
    float* hB = hA + (size_t)BB * RR;              // [B,R] fp32
    unsigned* bar = (unsigned*)(hB + (size_t)BB * RR);
    const size_t need = (size_t)BB * RR * 4 * 2 + 8192;

    if (ws_size >= need) {
        init_state_kernel<<<64, 512, 0, stream>>>(hA, start, bar);
        void* args[] = { (void*)&inputs, (void*)&Win, (void*)&Wrec, (void*)&bias,
                         (void*)&hA, (void*)&hB, (void*)&out, (void*)&bar };
        hipLaunchCooperativeKernel((void*)esn_f32, dim3(NBLK), dim3(NTHR),
                                   args, 0, stream);
    } else {
        init_h_kernel<<<(BB * RR + 255) / 256, 256, 0, stream>>>(hA, start);
        for (int t = 0; t < TT; ++t) {
            const float* hc = (t & 1) ? hB : hA;
            float*       hn = (t & 1) ? hA : hB;
            step_kernel<<<256, 512, 0, stream>>>(inputs, Win, Wrec, bias, hc, hn, out, t);
        }
    }
}